// Round 1
// baseline (473.524 us; speedup 1.0000x reference)
//
#include <hip/hip_runtime.h>
#include <hip/hip_bf16.h>

// ---------------------------------------------------------------------------
// GCN: 5 layers of  h = relu( norm_dst * scatter_add( (h@W * norm_src)[src] ) + b )
// Strategy: build CSR (dst-sorted) once per call, then per layer:
//   gemm_scale:  tmp = (h @ W) * norm_src        (fp32 vector-ALU tiled GEMM)
//   agg:         out = relu(norm_dst * sum_{in-edges} tmp[src] + b)  (CSR gather)
// ---------------------------------------------------------------------------

#define THREADS 256

__global__ __launch_bounds__(THREADS)
void count_deg_kernel(const int* __restrict__ src, const int* __restrict__ dst,
                      int* __restrict__ deg_src, int* __restrict__ deg_dst, int E) {
    int e = blockIdx.x * blockDim.x + threadIdx.x;
    if (e < E) {
        atomicAdd(&deg_src[src[e]], 1);
        atomicAdd(&deg_dst[dst[e]], 1);
    }
}

__global__ __launch_bounds__(THREADS)
void norm_kernel(const int* __restrict__ deg_src, const int* __restrict__ deg_dst,
                 float* __restrict__ norm_src, float* __restrict__ norm_dst, int N) {
    int n = blockIdx.x * blockDim.x + threadIdx.x;
    if (n < N) {
        int ds = deg_src[n]; if (ds < 1) ds = 1;
        int dd = deg_dst[n]; if (dd < 1) dd = 1;
        norm_src[n] = rsqrtf((float)ds);
        norm_dst[n] = rsqrtf((float)dd);
    }
}

// single-block exclusive scan of deg[0..n) -> row_ptr[0..n], row_ptr[n] = total
__global__ __launch_bounds__(1024)
void scan_kernel(const int* __restrict__ deg, int* __restrict__ row_ptr, int n) {
    __shared__ int sums[1024];
    int t = threadIdx.x;
    int T = 1024;
    int chunk = (n + T - 1) / T;
    int begin = t * chunk;
    int end   = begin + chunk; if (end > n) end = n; if (begin > n) begin = n;
    int s = 0;
    for (int i = begin; i < end; ++i) s += deg[i];
    sums[t] = s;
    __syncthreads();
    // inclusive Hillis-Steele scan over 1024 partials
    for (int offset = 1; offset < 1024; offset <<= 1) {
        int v = 0;
        if (t >= offset) v = sums[t - offset];
        __syncthreads();
        sums[t] += v;
        __syncthreads();
    }
    int run = sums[t] - s;   // exclusive prefix for this chunk
    for (int i = begin; i < end; ++i) { row_ptr[i] = run; run += deg[i]; }
    if (t == 1023) row_ptr[n] = sums[1023];
}

__global__ __launch_bounds__(THREADS)
void scatter_kernel(const int* __restrict__ src, const int* __restrict__ dst,
                    const int* __restrict__ row_ptr, int* __restrict__ cursor,
                    int* __restrict__ col, int E) {
    int e = blockIdx.x * blockDim.x + threadIdx.x;
    if (e < E) {
        int d = dst[e];
        int pos = atomicAdd(&cursor[d], 1);
        col[row_ptr[d] + pos] = src[e];
    }
}

// ---------------------------------------------------------------------------
// Tiled fp32 GEMM: out[m][n] = norm[m] * sum_k A[m][k] * W[k][n]
// A: M x K row-major, W: K x NOUT row-major.
// Thread map: tx covers NOUT/4 float4 columns, ty covers rows with strided
// blocking row = ty + NT_ROW*r so per-k A reads are consecutive across lanes.
// A tile stride padded to BK+4: keeps 16B-aligned stores, <=2-way conflicts.
// ---------------------------------------------------------------------------
template<int K, int NOUT, int BK, int TM>
__global__ __launch_bounds__(THREADS)
void gemm_scale_kernel(const float* __restrict__ A, const float* __restrict__ W,
                       const float* __restrict__ norm, float* __restrict__ out, int M) {
    constexpr int NT_COL = NOUT / 4;
    constexpr int NT_ROW = THREADS / NT_COL;
    constexpr int ROWS   = NT_ROW * TM;
    constexpr int BKP    = BK + 4;

    __shared__ float As[ROWS * BKP];
    __shared__ float Bs[BK * NOUT];

    const int tid = threadIdx.x;
    const int tx  = tid % NT_COL;
    const int ty  = tid / NT_COL;
    const int row0 = blockIdx.x * ROWS;

    float acc[TM][4];
#pragma unroll
    for (int r = 0; r < TM; ++r) { acc[r][0]=0.f; acc[r][1]=0.f; acc[r][2]=0.f; acc[r][3]=0.f; }

    for (int kb = 0; kb < K; kb += BK) {
        // stage A tile (ROWS x BK) as float4
        constexpr int A_VEC = ROWS * BK / 4;
#pragma unroll
        for (int i = tid; i < A_VEC; i += THREADS) {
            int r = (i * 4) / BK;
            int c = (i * 4) % BK;
            float4 v = make_float4(0.f, 0.f, 0.f, 0.f);
            int grow = row0 + r;
            if (grow < M) v = *(const float4*)&A[(size_t)grow * K + kb + c];
            *(float4*)&As[r * BKP + c] = v;
        }
        // stage B tile (BK x NOUT)
        constexpr int B_VEC = BK * NOUT / 4;
#pragma unroll
        for (int i = tid; i < B_VEC; i += THREADS) {
            int r = (i * 4) / NOUT;
            int c = (i * 4) % NOUT;
            *(float4*)&Bs[r * NOUT + c] = *(const float4*)&W[(size_t)(kb + r) * NOUT + c];
        }
        __syncthreads();

#pragma unroll
        for (int k = 0; k < BK; ++k) {
            float4 b = *(const float4*)&Bs[k * NOUT + tx * 4];
#pragma unroll
            for (int r = 0; r < TM; ++r) {
                float a = As[(ty + NT_ROW * r) * BKP + k];
                acc[r][0] += a * b.x;
                acc[r][1] += a * b.y;
                acc[r][2] += a * b.z;
                acc[r][3] += a * b.w;
            }
        }
        __syncthreads();
    }

#pragma unroll
    for (int r = 0; r < TM; ++r) {
        int row = row0 + ty + NT_ROW * r;
        if (row < M) {
            float s = norm[row];
            float4 o = make_float4(acc[r][0]*s, acc[r][1]*s, acc[r][2]*s, acc[r][3]*s);
            *(float4*)&out[(size_t)row * NOUT + tx * 4] = o;
        }
    }
}

// ---------------------------------------------------------------------------
// CSR aggregate: out[n][:] = relu(norm_dst[n] * sum_{j in row n} tmp[col[j]][:] + b)
// D/4 threads per node (float4 lanes), gather rows of tmp.
// ---------------------------------------------------------------------------
template<int D>
__global__ __launch_bounds__(THREADS)
void agg_kernel(const float* __restrict__ tmp, const int* __restrict__ row_ptr,
                const int* __restrict__ col, const float* __restrict__ norm_dst,
                const float* __restrict__ bias, float* __restrict__ out, int N) {
    constexpr int TPN = D / 4;          // threads per node
    constexpr int NPB = THREADS / TPN;  // nodes per block
    const int tid  = threadIdx.x;
    const int ln   = tid % TPN;
    const int g    = tid / TPN;
    const int node = blockIdx.x * NPB + g;
    if (node >= N) return;

    const int beg = row_ptr[node];
    const int end = row_ptr[node + 1];

    float4 acc = make_float4(0.f, 0.f, 0.f, 0.f);
    int j = beg;
    for (; j + 1 < end; j += 2) {
        int s0 = col[j];
        int s1 = col[j + 1];
        float4 v0 = *(const float4*)&tmp[(size_t)s0 * D + ln * 4];
        float4 v1 = *(const float4*)&tmp[(size_t)s1 * D + ln * 4];
        acc.x += v0.x + v1.x;
        acc.y += v0.y + v1.y;
        acc.z += v0.z + v1.z;
        acc.w += v0.w + v1.w;
    }
    if (j < end) {
        int s0 = col[j];
        float4 v0 = *(const float4*)&tmp[(size_t)s0 * D + ln * 4];
        acc.x += v0.x; acc.y += v0.y; acc.z += v0.z; acc.w += v0.w;
    }

    float nd = norm_dst[node];
    float4 b = *(const float4*)&bias[ln * 4];
    float4 o;
    o.x = fmaxf(acc.x * nd + b.x, 0.f);
    o.y = fmaxf(acc.y * nd + b.y, 0.f);
    o.z = fmaxf(acc.z * nd + b.z, 0.f);
    o.w = fmaxf(acc.w * nd + b.w, 0.f);
    *(float4*)&out[(size_t)node * D + ln * 4] = o;
}

extern "C" void kernel_launch(void* const* d_in, const int* in_sizes, int n_in,
                              void* d_out, int out_size, void* d_ws, size_t ws_size,
                              hipStream_t stream) {
    const float* x     = (const float*)d_in[0];
    const int*   edges = (const int*)d_in[1];
    const float* W1 = (const float*)d_in[2];  const float* b1 = (const float*)d_in[3];
    const float* W2 = (const float*)d_in[4];  const float* b2 = (const float*)d_in[5];
    const float* W3 = (const float*)d_in[6];  const float* b3 = (const float*)d_in[7];
    const float* W4 = (const float*)d_in[8];  const float* b4 = (const float*)d_in[9];
    const float* W5 = (const float*)d_in[10]; const float* b5 = (const float*)d_in[11];

    const int N = in_sizes[0] / 128;   // 50000
    const int E = in_sizes[1] / 2;     // 800000
    const int* src = edges;
    const int* dst = edges + E;

    // ---- carve workspace ----
    char* ws = (char*)d_ws;
    size_t off = 0;
    auto carve = [&](size_t bytes) -> void* {
        void* p = ws + off;
        off += (bytes + 255) & ~(size_t)255;
        return p;
    };
    float* tmp      = (float*)carve((size_t)N * 128 * 4);
    float* hbuf     = (float*)carve((size_t)N * 128 * 4);
    int*   degz     = (int*)carve((size_t)3 * N * 4);   // deg_src | deg_dst | cursor
    int*   deg_src  = degz;
    int*   deg_dst  = degz + N;
    int*   cursor   = degz + 2 * N;
    float* norm_src = (float*)carve((size_t)N * 4);
    float* norm_dst = (float*)carve((size_t)N * 4);
    int*   row_ptr  = (int*)carve((size_t)(N + 1) * 4);
    int*   col      = (int*)carve((size_t)E * 4);
    (void)ws_size;

    const int gridE = (E + THREADS - 1) / THREADS;
    const int gridN = (N + THREADS - 1) / THREADS;

    // ---- build degrees / norms / CSR ----
    hipMemsetAsync(degz, 0, (size_t)3 * N * 4, stream);
    count_deg_kernel<<<gridE, THREADS, 0, stream>>>(src, dst, deg_src, deg_dst, E);
    norm_kernel<<<gridN, THREADS, 0, stream>>>(deg_src, deg_dst, norm_src, norm_dst, N);
    scan_kernel<<<1, 1024, 0, stream>>>(deg_dst, row_ptr, N);
    scatter_kernel<<<gridE, THREADS, 0, stream>>>(src, dst, row_ptr, cursor, col, E);

    // ---- layers ----
    // L1: 128 -> 128
    {
        constexpr int ROWS = (THREADS / (128 / 4)) * 4;   // 32
        gemm_scale_kernel<128, 128, 32, 4><<<(N + ROWS - 1) / ROWS, THREADS, 0, stream>>>(x, W1, norm_src, tmp, N);
        constexpr int NPB = THREADS / (128 / 4);          // 8
        agg_kernel<128><<<(N + NPB - 1) / NPB, THREADS, 0, stream>>>(tmp, row_ptr, col, norm_dst, b1, hbuf, N);
    }
    // L2: 128 -> 64
    {
        constexpr int ROWS = (THREADS / (64 / 4)) * 4;    // 64
        gemm_scale_kernel<128, 64, 32, 4><<<(N + ROWS - 1) / ROWS, THREADS, 0, stream>>>(hbuf, W2, norm_src, tmp, N);
        constexpr int NPB = THREADS / (64 / 4);           // 16
        agg_kernel<64><<<(N + NPB - 1) / NPB, THREADS, 0, stream>>>(tmp, row_ptr, col, norm_dst, b2, hbuf, N);
    }
    // L3: 64 -> 32
    {
        constexpr int ROWS = (THREADS / (32 / 4)) * 4;    // 128
        gemm_scale_kernel<64, 32, 32, 4><<<(N + ROWS - 1) / ROWS, THREADS, 0, stream>>>(hbuf, W3, norm_src, tmp, N);
        constexpr int NPB = THREADS / (32 / 4);           // 32
        agg_kernel<32><<<(N + NPB - 1) / NPB, THREADS, 0, stream>>>(tmp, row_ptr, col, norm_dst, b3, hbuf, N);
    }
    // L4: 32 -> 16
    {
        constexpr int ROWS = (THREADS / (16 / 4)) * 4;    // 256
        gemm_scale_kernel<32, 16, 32, 4><<<(N + ROWS - 1) / ROWS, THREADS, 0, stream>>>(hbuf, W4, norm_src, tmp, N);
        constexpr int NPB = THREADS / (16 / 4);           // 64
        agg_kernel<16><<<(N + NPB - 1) / NPB, THREADS, 0, stream>>>(tmp, row_ptr, col, norm_dst, b4, hbuf, N);
    }
    // L5: 16 -> 16
    {
        constexpr int ROWS = (THREADS / (16 / 4)) * 4;    // 256
        gemm_scale_kernel<16, 16, 16, 4><<<(N + ROWS - 1) / ROWS, THREADS, 0, stream>>>(hbuf, W5, norm_src, tmp, N);
        constexpr int NPB = THREADS / (16 / 4);           // 64
        agg_kernel<16><<<(N + NPB - 1) / NPB, THREADS, 0, stream>>>(tmp, row_ptr, col, norm_dst, b5, (float*)d_out, N);
    }
}

// Round 2
// 405.395 us; speedup vs baseline: 1.1681x; 1.1681x over previous
//
#include <hip/hip_runtime.h>
#include <hip/hip_bf16.h>

// ---------------------------------------------------------------------------
// GCN: 5 layers of  h = relu( norm_dst * scatter_add( (h@W * norm_src)[src] ) + b )
// Strategy: build CSR (dst-sorted) once per call, then per layer:
//   gemm_scale:  tmp = (h @ W) * norm_src        (fp32 vector-ALU tiled GEMM)
//   agg:         out = relu(norm_dst * sum_{in-edges} tmp[src] + b)  (CSR gather)
// R2: hierarchical 3-phase scan (was: 76us single-block scan = 16% of runtime)
// ---------------------------------------------------------------------------

#define THREADS 256
#define SCAN_BLOCK 256

__global__ __launch_bounds__(THREADS)
void count_deg_kernel(const int* __restrict__ src, const int* __restrict__ dst,
                      int* __restrict__ deg_src, int* __restrict__ deg_dst, int E) {
    int e = blockIdx.x * blockDim.x + threadIdx.x;
    if (e < E) {
        atomicAdd(&deg_src[src[e]], 1);
        atomicAdd(&deg_dst[dst[e]], 1);
    }
}

// Phase A: per-block sums of deg_dst chunks (256 elems/block) + fused norm calc.
__global__ __launch_bounds__(SCAN_BLOCK)
void scanA_kernel(const int* __restrict__ deg_src, const int* __restrict__ deg_dst,
                  float* __restrict__ norm_src, float* __restrict__ norm_dst,
                  int* __restrict__ partials, int N) {
    __shared__ int red[SCAN_BLOCK];
    int t = threadIdx.x;
    int n = blockIdx.x * SCAN_BLOCK + t;
    int v = 0;
    if (n < N) {
        int dd = deg_dst[n];
        v = dd;
        int ds = deg_src[n];
        if (ds < 1) ds = 1;
        if (dd < 1) dd = 1;
        norm_src[n] = rsqrtf((float)ds);
        norm_dst[n] = rsqrtf((float)dd);
    }
    red[t] = v;
    __syncthreads();
#pragma unroll
    for (int off = SCAN_BLOCK / 2; off > 0; off >>= 1) {
        if (t < off) red[t] += red[t + off];
        __syncthreads();
    }
    if (t == 0) partials[blockIdx.x] = red[0];
}

// Phase B: single block scans the (<=256) partials -> exclusive block offsets;
// also writes row_ptr[N] = total.
__global__ __launch_bounds__(SCAN_BLOCK)
void scanB_kernel(int* __restrict__ partials, int* __restrict__ row_ptr,
                  int nb, int N) {
    __shared__ int s[SCAN_BLOCK];
    int t = threadIdx.x;
    int v = (t < nb) ? partials[t] : 0;
    s[t] = v;
    __syncthreads();
#pragma unroll
    for (int off = 1; off < SCAN_BLOCK; off <<= 1) {
        int u = 0;
        if (t >= off) u = s[t - off];
        __syncthreads();
        s[t] += u;
        __syncthreads();
    }
    if (t < nb) partials[t] = s[t] - v;   // exclusive prefix
    if (t == SCAN_BLOCK - 1) row_ptr[N] = s[t];
}

// Phase C: block-local exclusive scan of deg_dst chunk + block offset -> row_ptr.
__global__ __launch_bounds__(SCAN_BLOCK)
void scanC_kernel(const int* __restrict__ deg_dst, const int* __restrict__ partials,
                  int* __restrict__ row_ptr, int N) {
    __shared__ int s[SCAN_BLOCK];
    int t = threadIdx.x;
    int n = blockIdx.x * SCAN_BLOCK + t;
    int v = (n < N) ? deg_dst[n] : 0;
    s[t] = v;
    __syncthreads();
#pragma unroll
    for (int off = 1; off < SCAN_BLOCK; off <<= 1) {
        int u = 0;
        if (t >= off) u = s[t - off];
        __syncthreads();
        s[t] += u;
        __syncthreads();
    }
    if (n < N) row_ptr[n] = partials[blockIdx.x] + s[t] - v;
}

__global__ __launch_bounds__(THREADS)
void scatter_kernel(const int* __restrict__ src, const int* __restrict__ dst,
                    const int* __restrict__ row_ptr, int* __restrict__ cursor,
                    int* __restrict__ col, int E) {
    int e = blockIdx.x * blockDim.x + threadIdx.x;
    if (e < E) {
        int d = dst[e];
        int pos = atomicAdd(&cursor[d], 1);
        col[row_ptr[d] + pos] = src[e];
    }
}

// ---------------------------------------------------------------------------
// Tiled fp32 GEMM: out[m][n] = norm[m] * sum_k A[m][k] * W[k][n]
// ---------------------------------------------------------------------------
template<int K, int NOUT, int BK, int TM>
__global__ __launch_bounds__(THREADS)
void gemm_scale_kernel(const float* __restrict__ A, const float* __restrict__ W,
                       const float* __restrict__ norm, float* __restrict__ out, int M) {
    constexpr int NT_COL = NOUT / 4;
    constexpr int NT_ROW = THREADS / NT_COL;
    constexpr int ROWS   = NT_ROW * TM;
    constexpr int BKP    = BK + 4;

    __shared__ float As[ROWS * BKP];
    __shared__ float Bs[BK * NOUT];

    const int tid = threadIdx.x;
    const int tx  = tid % NT_COL;
    const int ty  = tid / NT_COL;
    const int row0 = blockIdx.x * ROWS;

    float acc[TM][4];
#pragma unroll
    for (int r = 0; r < TM; ++r) { acc[r][0]=0.f; acc[r][1]=0.f; acc[r][2]=0.f; acc[r][3]=0.f; }

    for (int kb = 0; kb < K; kb += BK) {
        constexpr int A_VEC = ROWS * BK / 4;
#pragma unroll
        for (int i = tid; i < A_VEC; i += THREADS) {
            int r = (i * 4) / BK;
            int c = (i * 4) % BK;
            float4 v = make_float4(0.f, 0.f, 0.f, 0.f);
            int grow = row0 + r;
            if (grow < M) v = *(const float4*)&A[(size_t)grow * K + kb + c];
            *(float4*)&As[r * BKP + c] = v;
        }
        constexpr int B_VEC = BK * NOUT / 4;
#pragma unroll
        for (int i = tid; i < B_VEC; i += THREADS) {
            int r = (i * 4) / NOUT;
            int c = (i * 4) % NOUT;
            *(float4*)&Bs[r * NOUT + c] = *(const float4*)&W[(size_t)(kb + r) * NOUT + c];
        }
        __syncthreads();

#pragma unroll
        for (int k = 0; k < BK; ++k) {
            float4 b = *(const float4*)&Bs[k * NOUT + tx * 4];
#pragma unroll
            for (int r = 0; r < TM; ++r) {
                float a = As[(ty + NT_ROW * r) * BKP + k];
                acc[r][0] += a * b.x;
                acc[r][1] += a * b.y;
                acc[r][2] += a * b.z;
                acc[r][3] += a * b.w;
            }
        }
        __syncthreads();
    }

#pragma unroll
    for (int r = 0; r < TM; ++r) {
        int row = row0 + ty + NT_ROW * r;
        if (row < M) {
            float s = norm[row];
            float4 o = make_float4(acc[r][0]*s, acc[r][1]*s, acc[r][2]*s, acc[r][3]*s);
            *(float4*)&out[(size_t)row * NOUT + tx * 4] = o;
        }
    }
}

// ---------------------------------------------------------------------------
// CSR aggregate: out[n][:] = relu(norm_dst[n] * sum_{j in row n} tmp[col[j]][:] + b)
// ---------------------------------------------------------------------------
template<int D>
__global__ __launch_bounds__(THREADS)
void agg_kernel(const float* __restrict__ tmp, const int* __restrict__ row_ptr,
                const int* __restrict__ col, const float* __restrict__ norm_dst,
                const float* __restrict__ bias, float* __restrict__ out, int N) {
    constexpr int TPN = D / 4;          // threads per node
    constexpr int NPB = THREADS / TPN;  // nodes per block
    const int tid  = threadIdx.x;
    const int ln   = tid % TPN;
    const int g    = tid / TPN;
    const int node = blockIdx.x * NPB + g;
    if (node >= N) return;

    const int beg = row_ptr[node];
    const int end = row_ptr[node + 1];

    float4 acc = make_float4(0.f, 0.f, 0.f, 0.f);
    int j = beg;
    for (; j + 1 < end; j += 2) {
        int s0 = col[j];
        int s1 = col[j + 1];
        float4 v0 = *(const float4*)&tmp[(size_t)s0 * D + ln * 4];
        float4 v1 = *(const float4*)&tmp[(size_t)s1 * D + ln * 4];
        acc.x += v0.x + v1.x;
        acc.y += v0.y + v1.y;
        acc.z += v0.z + v1.z;
        acc.w += v0.w + v1.w;
    }
    if (j < end) {
        int s0 = col[j];
        float4 v0 = *(const float4*)&tmp[(size_t)s0 * D + ln * 4];
        acc.x += v0.x; acc.y += v0.y; acc.z += v0.z; acc.w += v0.w;
    }

    float nd = norm_dst[node];
    float4 b = *(const float4*)&bias[ln * 4];
    float4 o;
    o.x = fmaxf(acc.x * nd + b.x, 0.f);
    o.y = fmaxf(acc.y * nd + b.y, 0.f);
    o.z = fmaxf(acc.z * nd + b.z, 0.f);
    o.w = fmaxf(acc.w * nd + b.w, 0.f);
    *(float4*)&out[(size_t)node * D + ln * 4] = o;
}

extern "C" void kernel_launch(void* const* d_in, const int* in_sizes, int n_in,
                              void* d_out, int out_size, void* d_ws, size_t ws_size,
                              hipStream_t stream) {
    const float* x     = (const float*)d_in[0];
    const int*   edges = (const int*)d_in[1];
    const float* W1 = (const float*)d_in[2];  const float* b1 = (const float*)d_in[3];
    const float* W2 = (const float*)d_in[4];  const float* b2 = (const float*)d_in[5];
    const float* W3 = (const float*)d_in[6];  const float* b3 = (const float*)d_in[7];
    const float* W4 = (const float*)d_in[8];  const float* b4 = (const float*)d_in[9];
    const float* W5 = (const float*)d_in[10]; const float* b5 = (const float*)d_in[11];

    const int N = in_sizes[0] / 128;   // 50000
    const int E = in_sizes[1] / 2;     // 800000
    const int* src = edges;
    const int* dst = edges + E;

    // ---- carve workspace ----
    char* ws = (char*)d_ws;
    size_t off = 0;
    auto carve = [&](size_t bytes) -> void* {
        void* p = ws + off;
        off += (bytes + 255) & ~(size_t)255;
        return p;
    };
    float* tmp      = (float*)carve((size_t)N * 128 * 4);
    float* hbuf     = (float*)carve((size_t)N * 128 * 4);
    int*   degz     = (int*)carve((size_t)3 * N * 4);   // deg_src | deg_dst | cursor
    int*   deg_src  = degz;
    int*   deg_dst  = degz + N;
    int*   cursor   = degz + 2 * N;
    float* norm_src = (float*)carve((size_t)N * 4);
    float* norm_dst = (float*)carve((size_t)N * 4);
    int*   row_ptr  = (int*)carve((size_t)(N + 1) * 4);
    int*   col      = (int*)carve((size_t)E * 4);
    int*   partials = (int*)carve((size_t)1024 * 4);
    (void)ws_size;

    const int gridE  = (E + THREADS - 1) / THREADS;
    const int gridSc = (N + SCAN_BLOCK - 1) / SCAN_BLOCK;   // 196 blocks

    // ---- build degrees / norms / CSR ----
    hipMemsetAsync(degz, 0, (size_t)3 * N * 4, stream);
    count_deg_kernel<<<gridE, THREADS, 0, stream>>>(src, dst, deg_src, deg_dst, E);
    scanA_kernel<<<gridSc, SCAN_BLOCK, 0, stream>>>(deg_src, deg_dst, norm_src, norm_dst, partials, N);
    scanB_kernel<<<1, SCAN_BLOCK, 0, stream>>>(partials, row_ptr, gridSc, N);
    scanC_kernel<<<gridSc, SCAN_BLOCK, 0, stream>>>(deg_dst, partials, row_ptr, N);
    scatter_kernel<<<gridE, THREADS, 0, stream>>>(src, dst, row_ptr, cursor, col, E);

    // ---- layers ----
    // L1: 128 -> 128
    {
        constexpr int ROWS = (THREADS / (128 / 4)) * 4;   // 32
        gemm_scale_kernel<128, 128, 32, 4><<<(N + ROWS - 1) / ROWS, THREADS, 0, stream>>>(x, W1, norm_src, tmp, N);
        constexpr int NPB = THREADS / (128 / 4);          // 8
        agg_kernel<128><<<(N + NPB - 1) / NPB, THREADS, 0, stream>>>(tmp, row_ptr, col, norm_dst, b1, hbuf, N);
    }
    // L2: 128 -> 64
    {
        constexpr int ROWS = (THREADS / (64 / 4)) * 4;    // 64
        gemm_scale_kernel<128, 64, 32, 4><<<(N + ROWS - 1) / ROWS, THREADS, 0, stream>>>(hbuf, W2, norm_src, tmp, N);
        constexpr int NPB = THREADS / (64 / 4);           // 16
        agg_kernel<64><<<(N + NPB - 1) / NPB, THREADS, 0, stream>>>(tmp, row_ptr, col, norm_dst, b2, hbuf, N);
    }
    // L3: 64 -> 32
    {
        constexpr int ROWS = (THREADS / (32 / 4)) * 4;    // 128
        gemm_scale_kernel<64, 32, 32, 4><<<(N + ROWS - 1) / ROWS, THREADS, 0, stream>>>(hbuf, W3, norm_src, tmp, N);
        constexpr int NPB = THREADS / (32 / 4);           // 32
        agg_kernel<32><<<(N + NPB - 1) / NPB, THREADS, 0, stream>>>(tmp, row_ptr, col, norm_dst, b3, hbuf, N);
    }
    // L4: 32 -> 16
    {
        constexpr int ROWS = (THREADS / (16 / 4)) * 4;    // 256
        gemm_scale_kernel<32, 16, 32, 4><<<(N + ROWS - 1) / ROWS, THREADS, 0, stream>>>(hbuf, W4, norm_src, tmp, N);
        constexpr int NPB = THREADS / (16 / 4);           // 64
        agg_kernel<16><<<(N + NPB - 1) / NPB, THREADS, 0, stream>>>(tmp, row_ptr, col, norm_dst, b4, hbuf, N);
    }
    // L5: 16 -> 16
    {
        constexpr int ROWS = (THREADS / (16 / 4)) * 4;    // 256
        gemm_scale_kernel<16, 16, 16, 4><<<(N + ROWS - 1) / ROWS, THREADS, 0, stream>>>(hbuf, W5, norm_src, tmp, N);
        constexpr int NPB = THREADS / (16 / 4);           // 64
        agg_kernel<16><<<(N + NPB - 1) / NPB, THREADS, 0, stream>>>(tmp, row_ptr, col, norm_dst, b5, (float*)d_out, N);
    }
}

// Round 3
// 379.424 us; speedup vs baseline: 1.2480x; 1.0684x over previous
//
#include <hip/hip_runtime.h>
#include <hip/hip_bf16.h>

// ---------------------------------------------------------------------------
// GCN: 5 layers of  h = relu( norm_dst * scatter_add( (h@W * norm_src)[src] ) + b )
// R3: atomic-free CSR build. R2's profile: count_deg = 66.6us with 50MB
// WRITE_SIZE -> device atomics execute at memory-side cache (~32B/atomic,
// ~24G atomics/s). Replace with LDS-privatized 16-bit packed histograms
// (128 blocks x 50KB LDS, 2 node ranges), non-atomic partial writes, and a
// rank-from-LDS scatter. Zero device-scope atomics anywhere.
// ---------------------------------------------------------------------------

#define THREADS 256
#define SCAN_BLOCK 256
#define HIST_B 128          // histogram blocks
#define NODES_PER_RANGE 25000
#define RANGE_WORDS 12500   // u32 words per range (2 nodes/word)
#define TOT_WORDS 25000     // words covering all N=50000 nodes

// ---------------------------------------------------------------------------
// Phase 1: per-block packed histograms of src and dst node ids.
// bins word w holds counts for nodes 2w (lo16) and 2w+1 (hi16).
// Partial counts <= chunk (6250) so no carry across halves.
// ---------------------------------------------------------------------------
__global__ __launch_bounds__(THREADS)
void hist_kernel(const int* __restrict__ src, const int* __restrict__ dst,
                 unsigned* __restrict__ p_src, unsigned* __restrict__ p_dst,
                 int E, int chunk) {
    __shared__ unsigned bins[RANGE_WORDS];   // 50 KB
    const int b = blockIdx.x;
    const int t = threadIdx.x;
    const int e0 = b * chunk;
    int e1 = e0 + chunk; if (e1 > E) e1 = E;

    for (int phase = 0; phase < 2; ++phase) {
        const int* idx = phase ? dst : src;
        unsigned* pout = phase ? p_dst : p_src;
        for (int r = 0; r < 2; ++r) {
            const int lo = r * NODES_PER_RANGE;
            for (int w = t; w < RANGE_WORDS; w += THREADS) bins[w] = 0;
            __syncthreads();
            for (int e = e0 + t; e < e1; e += THREADS) {
                int d = idx[e] - lo;
                if ((unsigned)d < (unsigned)NODES_PER_RANGE)
                    atomicAdd(&bins[d >> 1], 1u << ((d & 1) * 16));
            }
            __syncthreads();
            for (int w = t; w < RANGE_WORDS; w += THREADS)
                pout[(size_t)b * TOT_WORDS + r * RANGE_WORDS + w] = bins[w];
            __syncthreads();
        }
    }
}

// ---------------------------------------------------------------------------
// Phase 2: reduce partials -> degrees + norms; convert p_dst to exclusive
// per-block prefixes in place (for the rank-based scatter).
// One thread per packed word. Packed u32 adds are safe (halves < 2^16).
// ---------------------------------------------------------------------------
__global__ __launch_bounds__(THREADS)
void reduce_kernel(const unsigned* __restrict__ p_src, unsigned* __restrict__ p_dst,
                   int* __restrict__ deg_dst,
                   float* __restrict__ norm_src, float* __restrict__ norm_dst,
                   int N) {
    int w = blockIdx.x * blockDim.x + threadIdx.x;
    if (w >= TOT_WORDS) return;

    unsigned s = 0;
#pragma unroll 4
    for (int b = 0; b < HIST_B; ++b) s += p_src[(size_t)b * TOT_WORDS + w];

    unsigned run = 0;
#pragma unroll 4
    for (int b = 0; b < HIST_B; ++b) {
        size_t i = (size_t)b * TOT_WORDS + w;
        unsigned v = p_dst[i];
        p_dst[i] = run;
        run += v;
    }

    int n0 = 2 * w, n1 = 2 * w + 1;
    int dd0 = (int)(run & 0xffffu), dd1 = (int)(run >> 16);
    int ds0 = (int)(s & 0xffffu),  ds1 = (int)(s >> 16);
    deg_dst[n0] = dd0;
    norm_dst[n0] = rsqrtf((float)(dd0 < 1 ? 1 : dd0));
    norm_src[n0] = rsqrtf((float)(ds0 < 1 ? 1 : ds0));
    if (n1 < N) {
        deg_dst[n1] = dd1;
        norm_dst[n1] = rsqrtf((float)(dd1 < 1 ? 1 : dd1));
        norm_src[n1] = rsqrtf((float)(ds1 < 1 ? 1 : ds1));
    }
}

// ---------------------------------------------------------------------------
// 3-phase hierarchical scan of deg_dst -> row_ptr
// ---------------------------------------------------------------------------
__global__ __launch_bounds__(SCAN_BLOCK)
void scanA_kernel(const int* __restrict__ deg_dst, int* __restrict__ partials, int N) {
    __shared__ int red[SCAN_BLOCK];
    int t = threadIdx.x;
    int n = blockIdx.x * SCAN_BLOCK + t;
    int v = (n < N) ? deg_dst[n] : 0;
    red[t] = v;
    __syncthreads();
#pragma unroll
    for (int off = SCAN_BLOCK / 2; off > 0; off >>= 1) {
        if (t < off) red[t] += red[t + off];
        __syncthreads();
    }
    if (t == 0) partials[blockIdx.x] = red[0];
}

__global__ __launch_bounds__(SCAN_BLOCK)
void scanB_kernel(int* __restrict__ partials, int* __restrict__ row_ptr,
                  int nb, int N) {
    __shared__ int s[SCAN_BLOCK];
    int t = threadIdx.x;
    int v = (t < nb) ? partials[t] : 0;
    s[t] = v;
    __syncthreads();
#pragma unroll
    for (int off = 1; off < SCAN_BLOCK; off <<= 1) {
        int u = 0;
        if (t >= off) u = s[t - off];
        __syncthreads();
        s[t] += u;
        __syncthreads();
    }
    if (t < nb) partials[t] = s[t] - v;
    if (t == SCAN_BLOCK - 1) row_ptr[N] = s[t];
}

__global__ __launch_bounds__(SCAN_BLOCK)
void scanC_kernel(const int* __restrict__ deg_dst, const int* __restrict__ partials,
                  int* __restrict__ row_ptr, int N) {
    __shared__ int s[SCAN_BLOCK];
    int t = threadIdx.x;
    int n = blockIdx.x * SCAN_BLOCK + t;
    int v = (n < N) ? deg_dst[n] : 0;
    s[t] = v;
    __syncthreads();
#pragma unroll
    for (int off = 1; off < SCAN_BLOCK; off <<= 1) {
        int u = 0;
        if (t >= off) u = s[t - off];
        __syncthreads();
        s[t] += u;
        __syncthreads();
    }
    if (n < N) row_ptr[n] = partials[blockIdx.x] + s[t] - v;
}

// ---------------------------------------------------------------------------
// Phase 3: atomic-free scatter. Block b re-processes its edge chunk; LDS
// atomics assign local slots (any enumeration valid); global position =
// row_ptr[d] + cross-block exclusive prefix (from reduce) + local rank.
// ---------------------------------------------------------------------------
__global__ __launch_bounds__(THREADS)
void scatter_kernel(const int* __restrict__ src, const int* __restrict__ dst,
                    const int* __restrict__ row_ptr, const unsigned* __restrict__ p_dst,
                    int* __restrict__ col, int E, int chunk) {
    __shared__ unsigned bins[RANGE_WORDS];
    const int b = blockIdx.x;
    const int t = threadIdx.x;
    const int e0 = b * chunk;
    int e1 = e0 + chunk; if (e1 > E) e1 = E;

    for (int r = 0; r < 2; ++r) {
        const int lo = r * NODES_PER_RANGE;
        for (int w = t; w < RANGE_WORDS; w += THREADS) bins[w] = 0;
        __syncthreads();
        for (int e = e0 + t; e < e1; e += THREADS) {
            int d = dst[e];
            int dl = d - lo;
            if ((unsigned)dl < (unsigned)NODES_PER_RANGE) {
                unsigned sh = (unsigned)(d & 1) * 16u;
                unsigned old = atomicAdd(&bins[dl >> 1], 1u << sh);
                unsigned lr  = (old >> sh) & 0xffffu;
                unsigned pre = (p_dst[(size_t)b * TOT_WORDS + (d >> 1)] >> sh) & 0xffffu;
                col[row_ptr[d] + (int)pre + (int)lr] = src[e];
            }
        }
        __syncthreads();
    }
}

// ---------------------------------------------------------------------------
// Tiled fp32 GEMM: out[m][n] = norm[m] * sum_k A[m][k] * W[k][n]
// ---------------------------------------------------------------------------
template<int K, int NOUT, int BK, int TM>
__global__ __launch_bounds__(THREADS)
void gemm_scale_kernel(const float* __restrict__ A, const float* __restrict__ W,
                       const float* __restrict__ norm, float* __restrict__ out, int M) {
    constexpr int NT_COL = NOUT / 4;
    constexpr int NT_ROW = THREADS / NT_COL;
    constexpr int ROWS   = NT_ROW * TM;
    constexpr int BKP    = BK + 4;

    __shared__ float As[ROWS * BKP];
    __shared__ float Bs[BK * NOUT];

    const int tid = threadIdx.x;
    const int tx  = tid % NT_COL;
    const int ty  = tid / NT_COL;
    const int row0 = blockIdx.x * ROWS;

    float acc[TM][4];
#pragma unroll
    for (int r = 0; r < TM; ++r) { acc[r][0]=0.f; acc[r][1]=0.f; acc[r][2]=0.f; acc[r][3]=0.f; }

    for (int kb = 0; kb < K; kb += BK) {
        constexpr int A_VEC = ROWS * BK / 4;
#pragma unroll
        for (int i = tid; i < A_VEC; i += THREADS) {
            int r = (i * 4) / BK;
            int c = (i * 4) % BK;
            float4 v = make_float4(0.f, 0.f, 0.f, 0.f);
            int grow = row0 + r;
            if (grow < M) v = *(const float4*)&A[(size_t)grow * K + kb + c];
            *(float4*)&As[r * BKP + c] = v;
        }
        constexpr int B_VEC = BK * NOUT / 4;
#pragma unroll
        for (int i = tid; i < B_VEC; i += THREADS) {
            int r = (i * 4) / NOUT;
            int c = (i * 4) % NOUT;
            *(float4*)&Bs[r * NOUT + c] = *(const float4*)&W[(size_t)(kb + r) * NOUT + c];
        }
        __syncthreads();

#pragma unroll
        for (int k = 0; k < BK; ++k) {
            float4 b = *(const float4*)&Bs[k * NOUT + tx * 4];
#pragma unroll
            for (int r = 0; r < TM; ++r) {
                float a = As[(ty + NT_ROW * r) * BKP + k];
                acc[r][0] += a * b.x;
                acc[r][1] += a * b.y;
                acc[r][2] += a * b.z;
                acc[r][3] += a * b.w;
            }
        }
        __syncthreads();
    }

#pragma unroll
    for (int r = 0; r < TM; ++r) {
        int row = row0 + ty + NT_ROW * r;
        if (row < M) {
            float s = norm[row];
            float4 o = make_float4(acc[r][0]*s, acc[r][1]*s, acc[r][2]*s, acc[r][3]*s);
            *(float4*)&out[(size_t)row * NOUT + tx * 4] = o;
        }
    }
}

// ---------------------------------------------------------------------------
// CSR aggregate: out[n][:] = relu(norm_dst[n] * sum_{j in row n} tmp[col[j]][:] + b)
// ---------------------------------------------------------------------------
template<int D>
__global__ __launch_bounds__(THREADS)
void agg_kernel(const float* __restrict__ tmp, const int* __restrict__ row_ptr,
                const int* __restrict__ col, const float* __restrict__ norm_dst,
                const float* __restrict__ bias, float* __restrict__ out, int N) {
    constexpr int TPN = D / 4;          // threads per node
    constexpr int NPB = THREADS / TPN;  // nodes per block
    const int tid  = threadIdx.x;
    const int ln   = tid % TPN;
    const int g    = tid / TPN;
    const int node = blockIdx.x * NPB + g;
    if (node >= N) return;

    const int beg = row_ptr[node];
    const int end = row_ptr[node + 1];

    float4 acc = make_float4(0.f, 0.f, 0.f, 0.f);
    int j = beg;
    for (; j + 1 < end; j += 2) {
        int s0 = col[j];
        int s1 = col[j + 1];
        float4 v0 = *(const float4*)&tmp[(size_t)s0 * D + ln * 4];
        float4 v1 = *(const float4*)&tmp[(size_t)s1 * D + ln * 4];
        acc.x += v0.x + v1.x;
        acc.y += v0.y + v1.y;
        acc.z += v0.z + v1.z;
        acc.w += v0.w + v1.w;
    }
    if (j < end) {
        int s0 = col[j];
        float4 v0 = *(const float4*)&tmp[(size_t)s0 * D + ln * 4];
        acc.x += v0.x; acc.y += v0.y; acc.z += v0.z; acc.w += v0.w;
    }

    float nd = norm_dst[node];
    float4 b = *(const float4*)&bias[ln * 4];
    float4 o;
    o.x = fmaxf(acc.x * nd + b.x, 0.f);
    o.y = fmaxf(acc.y * nd + b.y, 0.f);
    o.z = fmaxf(acc.z * nd + b.z, 0.f);
    o.w = fmaxf(acc.w * nd + b.w, 0.f);
    *(float4*)&out[(size_t)node * D + ln * 4] = o;
}

extern "C" void kernel_launch(void* const* d_in, const int* in_sizes, int n_in,
                              void* d_out, int out_size, void* d_ws, size_t ws_size,
                              hipStream_t stream) {
    const float* x     = (const float*)d_in[0];
    const int*   edges = (const int*)d_in[1];
    const float* W1 = (const float*)d_in[2];  const float* b1 = (const float*)d_in[3];
    const float* W2 = (const float*)d_in[4];  const float* b2 = (const float*)d_in[5];
    const float* W3 = (const float*)d_in[6];  const float* b3 = (const float*)d_in[7];
    const float* W4 = (const float*)d_in[8];  const float* b4 = (const float*)d_in[9];
    const float* W5 = (const float*)d_in[10]; const float* b5 = (const float*)d_in[11];

    const int N = in_sizes[0] / 128;   // 50000
    const int E = in_sizes[1] / 2;     // 800000
    const int* src = edges;
    const int* dst = edges + E;

    // ---- carve workspace ----
    char* ws = (char*)d_ws;
    size_t off = 0;
    auto carve = [&](size_t bytes) -> void* {
        void* p = ws + off;
        off += (bytes + 255) & ~(size_t)255;
        return p;
    };
    float* tmp      = (float*)carve((size_t)N * 128 * 4);   // also aliased as hist scratch
    float* hbuf     = (float*)carve((size_t)N * 128 * 4);
    int*   deg_dst  = (int*)carve((size_t)N * 4);
    float* norm_src = (float*)carve((size_t)N * 4);
    float* norm_dst = (float*)carve((size_t)N * 4);
    int*   row_ptr  = (int*)carve((size_t)(N + 1) * 4);
    int*   col      = (int*)carve((size_t)E * 4);
    int*   partials = (int*)carve((size_t)1024 * 4);
    (void)ws_size;

    // hist scratch aliases tmp (dead until layer-1 GEMM): 2 x 12.8 MB
    unsigned* p_src = (unsigned*)tmp;
    unsigned* p_dst = p_src + (size_t)HIST_B * TOT_WORDS;

    const int chunk  = (E + HIST_B - 1) / HIST_B;           // 6250
    const int gridSc = (N + SCAN_BLOCK - 1) / SCAN_BLOCK;   // 196 blocks

    // ---- CSR build (no device-scope atomics anywhere) ----
    hist_kernel<<<HIST_B, THREADS, 0, stream>>>(src, dst, p_src, p_dst, E, chunk);
    reduce_kernel<<<(TOT_WORDS + THREADS - 1) / THREADS, THREADS, 0, stream>>>(
        p_src, p_dst, deg_dst, norm_src, norm_dst, N);
    scanA_kernel<<<gridSc, SCAN_BLOCK, 0, stream>>>(deg_dst, partials, N);
    scanB_kernel<<<1, SCAN_BLOCK, 0, stream>>>(partials, row_ptr, gridSc, N);
    scanC_kernel<<<gridSc, SCAN_BLOCK, 0, stream>>>(deg_dst, partials, row_ptr, N);
    scatter_kernel<<<HIST_B, THREADS, 0, stream>>>(src, dst, row_ptr, p_dst, col, E, chunk);

    // ---- layers ----
    // L1: 128 -> 128
    {
        constexpr int ROWS = (THREADS / (128 / 4)) * 4;   // 32
        gemm_scale_kernel<128, 128, 32, 4><<<(N + ROWS - 1) / ROWS, THREADS, 0, stream>>>(x, W1, norm_src, tmp, N);
        constexpr int NPB = THREADS / (128 / 4);          // 8
        agg_kernel<128><<<(N + NPB - 1) / NPB, THREADS, 0, stream>>>(tmp, row_ptr, col, norm_dst, b1, hbuf, N);
    }
    // L2: 128 -> 64
    {
        constexpr int ROWS = (THREADS / (64 / 4)) * 4;    // 64
        gemm_scale_kernel<128, 64, 32, 4><<<(N + ROWS - 1) / ROWS, THREADS, 0, stream>>>(hbuf, W2, norm_src, tmp, N);
        constexpr int NPB = THREADS / (64 / 4);           // 16
        agg_kernel<64><<<(N + NPB - 1) / NPB, THREADS, 0, stream>>>(tmp, row_ptr, col, norm_dst, b2, hbuf, N);
    }
    // L3: 64 -> 32
    {
        constexpr int ROWS = (THREADS / (32 / 4)) * 4;    // 128
        gemm_scale_kernel<64, 32, 32, 4><<<(N + ROWS - 1) / ROWS, THREADS, 0, stream>>>(hbuf, W3, norm_src, tmp, N);
        constexpr int NPB = THREADS / (32 / 4);           // 32
        agg_kernel<32><<<(N + NPB - 1) / NPB, THREADS, 0, stream>>>(tmp, row_ptr, col, norm_dst, b3, hbuf, N);
    }
    // L4: 32 -> 16
    {
        constexpr int ROWS = (THREADS / (16 / 4)) * 4;    // 256
        gemm_scale_kernel<32, 16, 32, 4><<<(N + ROWS - 1) / ROWS, THREADS, 0, stream>>>(hbuf, W4, norm_src, tmp, N);
        constexpr int NPB = THREADS / (16 / 4);           // 64
        agg_kernel<16><<<(N + NPB - 1) / NPB, THREADS, 0, stream>>>(tmp, row_ptr, col, norm_dst, b4, hbuf, N);
    }
    // L5: 16 -> 16
    {
        constexpr int ROWS = (THREADS / (16 / 4)) * 4;    // 256
        gemm_scale_kernel<16, 16, 16, 4><<<(N + ROWS - 1) / ROWS, THREADS, 0, stream>>>(hbuf, W5, norm_src, tmp, N);
        constexpr int NPB = THREADS / (16 / 4);           // 64
        agg_kernel<16><<<(N + NPB - 1) / NPB, THREADS, 0, stream>>>(tmp, row_ptr, col, norm_dst, b5, (float*)d_out, N);
    }
}